// Round 1
// baseline (387.864 us; speedup 1.0000x reference)
//
#include <hip/hip_runtime.h>
#include <math.h>
#include <stdint.h>

typedef __bf16 bf16;
typedef __bf16 bf16x4 __attribute__((ext_vector_type(4)));
typedef __bf16 bf16x8 __attribute__((ext_vector_type(8)));
typedef float  f32x4  __attribute__((ext_vector_type(4)));

#define QSCALE 0.18033688011112042f /* 0.125 * log2(e): softmax done base-2 */

// ---------------- workspace layout (bytes) ----------------
#define XB_OFF    ((size_t)0)            // x bf16       4096x1024  (8 MB)
#define WQKV_OFF  ((size_t)8388608)      // W_qkv bf16   3072x1024  (6 MB)
#define WO_OFF    ((size_t)14680064)     // W_o bf16     1024x1024  (2 MB)
#define QB_OFF    ((size_t)16777216)     // Q bf16 (B,H,S,D) rope+scaled (8 MB)
#define KB_OFF    ((size_t)25165824)     // K bf16 (B,H,S,D) rope        (8 MB)
#define VB_OFF    ((size_t)33554432)     // V bf16 (B,H,S,D)             (8 MB)
#define YB_OFF    ((size_t)41943040)     // attn out bf16 (B,S,E)        (8 MB)
#define COS_OFF   ((size_t)50331648)     // 2048x32 f32
#define SIN_OFF   ((size_t)50593792)     // 2048x32 f32

__device__ __forceinline__ void gload_lds16(const void* g, void* l) {
  // async global->LDS, 16B/lane, LDS dst = wave-uniform base + lane*16
  __builtin_amdgcn_global_load_lds((const __attribute__((address_space(1))) void*)g,
                                   (__attribute__((address_space(3))) void*)l,
                                   16, 0, 0);
}

__global__ void cvt_f32_bf16(const float* __restrict__ src, bf16* __restrict__ dst, int n4) {
  int i = blockIdx.x * blockDim.x + threadIdx.x;
  if (i >= n4) return;
  float4 v = ((const float4*)src)[i];
  bf16x4 o = {(bf16)v.x, (bf16)v.y, (bf16)v.z, (bf16)v.w};
  *(bf16x4*)(dst + (size_t)i * 4) = o;
}

__global__ void rope_table(float* __restrict__ cosT, float* __restrict__ sinT) {
  int i = blockIdx.x * blockDim.x + threadIdx.x;   // 2048*32 threads
  int s = i >> 5, f = i & 31;
  // theta = 10000^(-f/32) = 2^(-f*log2(1e4)/32)
  float theta = exp2f(-(float)f * (13.287712379549449f / 32.0f));
  float ang = (float)s * theta;
  cosT[i] = cosf(ang);
  sinT[i] = sinf(ang);
}

// ---------------------------------------------------------------------------
// NT GEMM: C[m,n] = sum_k A[m,k]*B[n,k].  m97 structure: 128x128 tile, BK=32,
// 4 waves each 64x64 (4x4 grid of 16x16x32 bf16 MFMA), global_load_lds(16B).
// EPI==0: QKV epilogue (split + RoPE + scale-fold + scatter to (B,H,S,D) bf16)
// EPI==1: plain fp32 store
// ---------------------------------------------------------------------------
template <int EPI>
__global__ __launch_bounds__(256) void gemm_nt(
    const bf16* __restrict__ A, const bf16* __restrict__ Bw, float* __restrict__ Cout,
    bf16* __restrict__ Qb, bf16* __restrict__ Kb, bf16* __restrict__ Vb,
    const float* __restrict__ cosT, const float* __restrict__ sinT,
    int M, int N, int K)
{
  __shared__ bf16 sA[128 * 32];
  __shared__ bf16 sB[128 * 32];

  const int tid  = threadIdx.x;
  const int w    = tid >> 6;
  const int lane = tid & 63;
  const int quad = lane >> 4;
  const int l16  = lane & 15;
  const int wm   = (w >> 1) << 6;
  const int wn   = (w & 1) << 6;
  const int tm   = blockIdx.y << 7;
  const int tn   = blockIdx.x << 7;
  const int srow = lane >> 2;        // staging: lane -> (row within 16, col8)
  const int scol = (lane & 3) << 3;

  f32x4 zero4 = {0.f, 0.f, 0.f, 0.f};
  f32x4 acc[4][4];
#pragma unroll
  for (int i = 0; i < 4; ++i)
#pragma unroll
    for (int j = 0; j < 4; ++j) acc[i][j] = zero4;

  const bf16* Abase = A + (size_t)tm * K;
  const bf16* Bbase = Bw + (size_t)tn * K;

  for (int k0 = 0; k0 < K; k0 += 32) {
#pragma unroll
    for (int c = 0; c < 2; ++c) {
      const int chunk = (w << 1) + c;          // 8 chunks of 16 rows each
      const int row   = (chunk << 4) + srow;
      gload_lds16(Abase + (size_t)row * K + (k0 + scol), &sA[chunk * 512]);
      gload_lds16(Bbase + (size_t)row * K + (k0 + scol), &sB[chunk * 512]);
    }
    __syncthreads();   // drains vmcnt (global_load_lds) + barrier
    bf16x8 afrag[4], bfrag[4];
#pragma unroll
    for (int i = 0; i < 4; ++i)
      afrag[i] = *(const bf16x8*)&sA[(wm + i * 16 + l16) * 32 + quad * 8];
#pragma unroll
    for (int j = 0; j < 4; ++j)
      bfrag[j] = *(const bf16x8*)&sB[(wn + j * 16 + l16) * 32 + quad * 8];
#pragma unroll
    for (int i = 0; i < 4; ++i)
#pragma unroll
      for (int j = 0; j < 4; ++j)
        acc[i][j] = __builtin_amdgcn_mfma_f32_16x16x32_bf16(afrag[i], bfrag[j], acc[i][j], 0, 0, 0);
    __syncthreads();
  }

  if constexpr (EPI == 0) {
    // C/D layout: col = lane&15 (within 16-tile), row = quad*4 + r
#pragma unroll
    for (int j = 0; j < 4; ++j) {
      const int n = tn + wn + j * 16 + l16;    // global output col in [0,3072)
      const int g = n >> 10;                   // 0:q 1:k 2:v  (wave-uniform)
      const int e = n & 1023;
      const int h = e >> 6;
      const int d = e & 63;
      const int f = d >> 1;
      const float sgn = (d & 1) ? 1.0f : -1.0f;
      bf16* dst = (g == 2) ? Vb : ((g == 0) ? Qb : Kb);
#pragma unroll
      for (int i = 0; i < 4; ++i) {
#pragma unroll
        for (int r = 0; r < 4; ++r) {
          const int m = tm + wm + i * 16 + quad * 4 + r;
          const int b = m >> 11;
          const int s = m & 2047;
          float v  = acc[i][j][r];
          float vo = __shfl_xor(v, 1);         // RoPE pair partner (col^1 = lane^1)
          float outv;
          if (g == 2) {
            outv = v;
          } else {
            float c  = cosT[s * 32 + f];
            float sn = sinT[s * 32 + f];
            outv = v * c + sgn * vo * sn;      // even d: v*c - vo*s ; odd: v*c + vo*s
            if (g == 0) outv *= QSCALE;        // fold 1/sqrt(D)*log2(e) into Q
          }
          dst[((size_t)(b * 16 + h) * 2048 + s) * 64 + d] = (bf16)outv;
        }
      }
    }
  } else {
#pragma unroll
    for (int i = 0; i < 4; ++i)
#pragma unroll
      for (int j = 0; j < 4; ++j)
#pragma unroll
        for (int r = 0; r < 4; ++r) {
          const int m = tm + wm + i * 16 + quad * 4 + r;
          const int n = tn + wn + j * 16 + l16;
          Cout[(size_t)m * N + n] = acc[i][j][r];
        }
  }
}

// ---------------------------------------------------------------------------
// Causal flash attention. Q pre-scaled by 0.125*log2(e); softmax in base 2.
// Block: one (b,h), 64 q-rows; 4 waves x 16 rows. KV tiles of 64.
// LDS stride 72 (=64+8) keeps ds_read_b128 16B-aligned and breaks the
// 128B-row-stride bank conflict.
// ---------------------------------------------------------------------------
#define LDP 72

__global__ __launch_bounds__(256) void attn_fwd(
    const bf16* __restrict__ Qb, const bf16* __restrict__ Kb,
    const bf16* __restrict__ Vb, bf16* __restrict__ Yb)
{
  __shared__ bf16 sQ[64 * LDP];
  __shared__ bf16 sK[64 * LDP];
  __shared__ bf16 sVt[64 * LDP];   // transposed: sVt[d][k]
  __shared__ bf16 sP[64 * LDP];

  const int qt  = blockIdx.x;      // q-tile 0..31
  const int bh  = blockIdx.y;      // b*16+h, 0..31
  const int tid = threadIdx.x;
  const int w    = tid >> 6;
  const int lane = tid & 63;
  const int quad = lane >> 4;
  const int l16  = lane & 15;

  const size_t head = (size_t)bh * 2048 * 64;

  { // stage Q tile (coalesced 16B loads)
    const bf16* src = Qb + head + (size_t)qt * 64 * 64;
#pragma unroll
    for (int c = 0; c < 2; ++c) {
      int idx = c * 256 + tid;             // 512 chunks of 8 elems
      int row = idx >> 3, col = (idx & 7) << 3;
      *(bf16x8*)&sQ[row * LDP + col] = *(const bf16x8*)&src[row * 64 + col];
    }
  }
  __syncthreads();
  // A-operand frags: A[m=lane&15][k=quad*8+j], strip = wave's 16 q-rows
  bf16x8 aq0 = *(const bf16x8*)&sQ[(w * 16 + l16) * LDP + quad * 8];
  bf16x8 aq1 = *(const bf16x8*)&sQ[(w * 16 + l16) * LDP + 32 + quad * 8];

  f32x4 zero4 = {0.f, 0.f, 0.f, 0.f};
  f32x4 o[4] = {zero4, zero4, zero4, zero4};
  float mi[4] = {-3.0e38f, -3.0e38f, -3.0e38f, -3.0e38f};
  float li[4] = {0.f, 0.f, 0.f, 0.f};

  const int qrow = qt * 64 + w * 16 + quad * 4;   // + r = global q position

  for (int kt = 0; kt <= qt; ++kt) {
    const bf16* ksrc = Kb + head + (size_t)kt * 64 * 64;
    const bf16* vsrc = Vb + head + (size_t)kt * 64 * 64;
#pragma unroll
    for (int c = 0; c < 2; ++c) {
      int idx = c * 256 + tid;
      int row = idx >> 3, col = (idx & 7) << 3;
      *(bf16x8*)&sK[row * LDP + col] = *(const bf16x8*)&ksrc[row * 64 + col];
      bf16x8 vv = *(const bf16x8*)&vsrc[row * 64 + col];
#pragma unroll
      for (int jj = 0; jj < 8; ++jj) sVt[(col + jj) * LDP + row] = vv[jj];
    }
    __syncthreads();

    // S = Q K^T (log2 domain, pre-scaled)
    f32x4 sv[4];
#pragma unroll
    for (int i = 0; i < 4; ++i) {
      bf16x8 b0 = *(const bf16x8*)&sK[(i * 16 + l16) * LDP + quad * 8];
      bf16x8 b1 = *(const bf16x8*)&sK[(i * 16 + l16) * LDP + 32 + quad * 8];
      f32x4 cacc = zero4;
      cacc = __builtin_amdgcn_mfma_f32_16x16x32_bf16(aq0, b0, cacc, 0, 0, 0);
      cacc = __builtin_amdgcn_mfma_f32_16x16x32_bf16(aq1, b1, cacc, 0, 0, 0);
      sv[i] = cacc;
    }

    if (kt == qt) {  // diagonal tile: causal mask
#pragma unroll
      for (int i = 0; i < 4; ++i) {
        int kcol = kt * 64 + i * 16 + l16;
#pragma unroll
        for (int r = 0; r < 4; ++r)
          sv[i][r] = (kcol > qrow + r) ? -3.0e38f : sv[i][r];
      }
    }

    // online softmax; row r owned by the 16 lanes of this quad
    float pv[4][4];
#pragma unroll
    for (int r = 0; r < 4; ++r) {
      float vr = fmaxf(fmaxf(sv[0][r], sv[1][r]), fmaxf(sv[2][r], sv[3][r]));
#pragma unroll
      for (int off = 1; off < 16; off <<= 1) vr = fmaxf(vr, __shfl_xor(vr, off));
      float mn = fmaxf(mi[r], vr);
      float al = exp2f(mi[r] - mn);
      float rs = 0.f;
#pragma unroll
      for (int i = 0; i < 4; ++i) {
        float p = exp2f(sv[i][r] - mn);
        pv[i][r] = p;
        rs += p;
      }
#pragma unroll
      for (int off = 1; off < 16; off <<= 1) rs += __shfl_xor(rs, off);
      li[r] = li[r] * al + rs;
      mi[r] = mn;
#pragma unroll
      for (int i = 0; i < 4; ++i) o[i][r] *= al;
    }

    // P: C-layout -> LDS -> A-layout (each wave round-trips only its own strip)
#pragma unroll
    for (int i = 0; i < 4; ++i)
#pragma unroll
      for (int r = 0; r < 4; ++r)
        sP[(w * 16 + quad * 4 + r) * LDP + i * 16 + l16] = (bf16)pv[i][r];

    __syncthreads();  // conservative round-1 ordering guarantee for sP

    bf16x8 ap0 = *(const bf16x8*)&sP[(w * 16 + l16) * LDP + quad * 8];
    bf16x8 ap1 = *(const bf16x8*)&sP[(w * 16 + l16) * LDP + 32 + quad * 8];
#pragma unroll
    for (int i = 0; i < 4; ++i) {  // O += P V ; B[k][n=d] from sVt[d][k]
      bf16x8 b0 = *(const bf16x8*)&sVt[(i * 16 + l16) * LDP + quad * 8];
      bf16x8 b1 = *(const bf16x8*)&sVt[(i * 16 + l16) * LDP + 32 + quad * 8];
      o[i] = __builtin_amdgcn_mfma_f32_16x16x32_bf16(ap0, b0, o[i], 0, 0, 0);
      o[i] = __builtin_amdgcn_mfma_f32_16x16x32_bf16(ap1, b1, o[i], 0, 0, 0);
    }
    __syncthreads();
  }

  const int b = bh >> 4, h = bh & 15;
#pragma unroll
  for (int r = 0; r < 4; ++r) {
    float inv = 1.0f / li[r];
    int s = qt * 64 + w * 16 + quad * 4 + r;
    size_t base = ((size_t)(b * 2048 + s)) * 1024 + h * 64;
#pragma unroll
    for (int i = 0; i < 4; ++i)
      Yb[base + i * 16 + l16] = (bf16)(o[i][r] * inv);
  }
}

// ---------------------------------------------------------------------------
extern "C" void kernel_launch(void* const* d_in, const int* in_sizes, int n_in,
                              void* d_out, int out_size, void* d_ws, size_t ws_size,
                              hipStream_t stream) {
  (void)in_sizes; (void)n_in; (void)out_size; (void)ws_size;
  const float* x    = (const float*)d_in[0];
  const float* wqkv = (const float*)d_in[1];
  const float* wo   = (const float*)d_in[2];
  float* out = (float*)d_out;
  char* ws = (char*)d_ws;

  bf16* Xb    = (bf16*)(ws + XB_OFF);
  bf16* Wqkvb = (bf16*)(ws + WQKV_OFF);
  bf16* Wob   = (bf16*)(ws + WO_OFF);
  bf16* Qb    = (bf16*)(ws + QB_OFF);
  bf16* Kb    = (bf16*)(ws + KB_OFF);
  bf16* Vb    = (bf16*)(ws + VB_OFF);
  bf16* Yb    = (bf16*)(ws + YB_OFF);
  float* cosT = (float*)(ws + COS_OFF);
  float* sinT = (float*)(ws + SIN_OFF);

  rope_table<<<(2048 * 32) / 256, 256, 0, stream>>>(cosT, sinT);
  cvt_f32_bf16<<<4096, 256, 0, stream>>>(x,    Xb,    (4096 * 1024) / 4);
  cvt_f32_bf16<<<3072, 256, 0, stream>>>(wqkv, Wqkvb, (3072 * 1024) / 4);
  cvt_f32_bf16<<<1024, 256, 0, stream>>>(wo,   Wob,   (1024 * 1024) / 4);

  // QKV projection + fused RoPE/split/transpose epilogue
  gemm_nt<0><<<dim3(24, 32), 256, 0, stream>>>(Xb, Wqkvb, nullptr, Qb, Kb, Vb,
                                               cosT, sinT, 4096, 3072, 1024);
  // causal flash attention
  attn_fwd<<<dim3(32, 32), 256, 0, stream>>>(Qb, Kb, Vb, Yb);
  // output projection
  gemm_nt<1><<<dim3(8, 32), 256, 0, stream>>>(Yb, Wob, out, nullptr, nullptr, nullptr,
                                              nullptr, nullptr, 4096, 1024, 1024);
}

// Round 2
// 244.234 us; speedup vs baseline: 1.5881x; 1.5881x over previous
//
#include <hip/hip_runtime.h>
#include <math.h>
#include <stdint.h>

typedef __bf16 bf16;
typedef __bf16 bf16x4 __attribute__((ext_vector_type(4)));
typedef __bf16 bf16x8 __attribute__((ext_vector_type(8)));
typedef float  f32x4  __attribute__((ext_vector_type(4)));

#define QSCALE 0.18033688011112042f /* 0.125 * log2(e): softmax done base-2 */

// ---------------- workspace layout (bytes) ----------------
#define XB_OFF    ((size_t)0)            // x bf16       4096x1024  (8 MB)
#define WQKV_OFF  ((size_t)8388608)      // W_qkv bf16   3072x1024  (6 MB)
#define WO_OFF    ((size_t)14680064)     // W_o bf16     1024x1024  (2 MB)
#define QB_OFF    ((size_t)16777216)     // Q bf16 (B,H,S,D) rope+scaled (8 MB)
#define KB_OFF    ((size_t)25165824)     // K bf16 (B,H,S,D) rope        (8 MB)
#define VT_OFF    ((size_t)33554432)     // V^T bf16 (B,H,D,S)           (8 MB)
#define YB_OFF    ((size_t)41943040)     // attn out bf16 (B,S,E)        (8 MB)
#define COS_OFF   ((size_t)50331648)     // 2048x32 f32
#define SIN_OFF   ((size_t)50593792)     // 2048x32 f32

__device__ __forceinline__ void gload_lds16(const void* g, void* l) {
  // async global->LDS, 16B/lane, LDS dst = wave-uniform base + lane*16
  __builtin_amdgcn_global_load_lds((const __attribute__((address_space(1))) void*)g,
                                   (__attribute__((address_space(3))) void*)l,
                                   16, 0, 0);
}

__global__ void cvt_f32_bf16(const float* __restrict__ src, bf16* __restrict__ dst, int n4) {
  int i = blockIdx.x * blockDim.x + threadIdx.x;
  if (i >= n4) return;
  float4 v = ((const float4*)src)[i];
  bf16x4 o = {(bf16)v.x, (bf16)v.y, (bf16)v.z, (bf16)v.w};
  *(bf16x4*)(dst + (size_t)i * 4) = o;
}

__global__ void rope_table(float* __restrict__ cosT, float* __restrict__ sinT) {
  int i = blockIdx.x * blockDim.x + threadIdx.x;   // 2048*32 threads
  int s = i >> 5, f = i & 31;
  float theta = exp2f(-(float)f * (13.287712379549449f / 32.0f));
  float ang = (float)s * theta;
  cosT[i] = cosf(ang);
  sinT[i] = sinf(ang);
}

// ---------------------------------------------------------------------------
// NT GEMM (m97 structure): 128x128 tile, BK=32, global_load_lds(16B).
// EPI==0: QKV epilogue (split + RoPE + scale-fold; V stored TRANSPOSED (B,H,D,S))
// EPI==1: plain fp32 store
// ---------------------------------------------------------------------------
template <int EPI>
__global__ __launch_bounds__(256) void gemm_nt(
    const bf16* __restrict__ A, const bf16* __restrict__ Bw, float* __restrict__ Cout,
    bf16* __restrict__ Qb, bf16* __restrict__ Kb, bf16* __restrict__ Vt,
    const float* __restrict__ cosT, const float* __restrict__ sinT,
    int M, int N, int K)
{
  __shared__ bf16 sA[128 * 32];
  __shared__ bf16 sB[128 * 32];

  const int tid  = threadIdx.x;
  const int w    = tid >> 6;
  const int lane = tid & 63;
  const int quad = lane >> 4;
  const int l16  = lane & 15;
  const int wm   = (w >> 1) << 6;
  const int wn   = (w & 1) << 6;
  const int tm   = blockIdx.y << 7;
  const int tn   = blockIdx.x << 7;
  const int srow = lane >> 2;
  const int scol = (lane & 3) << 3;

  f32x4 zero4 = {0.f, 0.f, 0.f, 0.f};
  f32x4 acc[4][4];
#pragma unroll
  for (int i = 0; i < 4; ++i)
#pragma unroll
    for (int j = 0; j < 4; ++j) acc[i][j] = zero4;

  const bf16* Abase = A + (size_t)tm * K;
  const bf16* Bbase = Bw + (size_t)tn * K;

  for (int k0 = 0; k0 < K; k0 += 32) {
#pragma unroll
    for (int c = 0; c < 2; ++c) {
      const int chunk = (w << 1) + c;
      const int row   = (chunk << 4) + srow;
      gload_lds16(Abase + (size_t)row * K + (k0 + scol), &sA[chunk * 512]);
      gload_lds16(Bbase + (size_t)row * K + (k0 + scol), &sB[chunk * 512]);
    }
    __syncthreads();
    bf16x8 afrag[4], bfrag[4];
#pragma unroll
    for (int i = 0; i < 4; ++i)
      afrag[i] = *(const bf16x8*)&sA[(wm + i * 16 + l16) * 32 + quad * 8];
#pragma unroll
    for (int j = 0; j < 4; ++j)
      bfrag[j] = *(const bf16x8*)&sB[(wn + j * 16 + l16) * 32 + quad * 8];
#pragma unroll
    for (int i = 0; i < 4; ++i)
#pragma unroll
      for (int j = 0; j < 4; ++j)
        acc[i][j] = __builtin_amdgcn_mfma_f32_16x16x32_bf16(afrag[i], bfrag[j], acc[i][j], 0, 0, 0);
    __syncthreads();
  }

  if constexpr (EPI == 0) {
    // C/D layout: col = lane&15, row = quad*4 + r
#pragma unroll
    for (int j = 0; j < 4; ++j) {
      const int n = tn + wn + j * 16 + l16;    // [0,3072)
      const int g = n >> 10;                   // 0:q 1:k 2:v
      const int e = n & 1023;
      const int h = e >> 6;
      const int d = e & 63;
      const int f = d >> 1;
      const float sgn = (d & 1) ? 1.0f : -1.0f;
#pragma unroll
      for (int i = 0; i < 4; ++i) {
#pragma unroll
        for (int r = 0; r < 4; ++r) {
          const int m = tm + wm + i * 16 + quad * 4 + r;
          const int b = m >> 11;
          const int s = m & 2047;
          float v  = acc[i][j][r];
          float vo = __shfl_xor(v, 1);         // RoPE pair partner
          if (g == 2) {
            Vt[((size_t)(b * 16 + h) * 64 + d) * 2048 + s] = (bf16)v;   // transposed
          } else {
            float c  = cosT[s * 32 + f];
            float sn = sinT[s * 32 + f];
            float outv = v * c + sgn * vo * sn;
            if (g == 0) {
              outv *= QSCALE;
              Qb[((size_t)(b * 16 + h) * 2048 + s) * 64 + d] = (bf16)outv;
            } else {
              Kb[((size_t)(b * 16 + h) * 2048 + s) * 64 + d] = (bf16)outv;
            }
          }
        }
      }
    }
  } else {
#pragma unroll
    for (int i = 0; i < 4; ++i)
#pragma unroll
      for (int j = 0; j < 4; ++j)
#pragma unroll
        for (int r = 0; r < 4; ++r) {
          const int m = tm + wm + i * 16 + quad * 4 + r;
          const int n = tn + wn + j * 16 + l16;
          Cout[(size_t)m * N + n] = acc[i][j][r];
        }
  }
}

// ---------------------------------------------------------------------------
// Causal flash attention, restructured:
//  - block handles q-tiles {p, 31-p} -> uniform 33 k-iterations/block
//  - K and V^T staged via global_load_lds into XOR-swizzled unpadded LDS
//  - double-buffered K/V^T, ONE barrier per k-tile, loads overlap compute
//  - sP is wave-private: no barrier between write and A-frag read
// ---------------------------------------------------------------------------
__global__ __launch_bounds__(256) void attn_fwd(
    const bf16* __restrict__ Qb, const bf16* __restrict__ Kb,
    const bf16* __restrict__ Vt, bf16* __restrict__ Yb)
{
  __shared__ bf16 sK[2][64 * 64];
  __shared__ bf16 sV[2][64 * 64];   // V^T tile: row d, col k (swizzled)
  __shared__ bf16 sP[64 * 72];

  const int p   = blockIdx.x;      // 0..15
  const int bh  = blockIdx.y;      // 0..31
  const int tid = threadIdx.x;
  const int w    = tid >> 6;
  const int lane = tid & 63;
  const int quad = lane >> 4;
  const int l16  = lane & 15;

  const size_t head = (size_t)bh * 2048 * 64;   // same stride for Q,K,V^T
  const bf16* khead = Kb + head;
  const bf16* vhead = Vt + head;

  // staging geometry: lane i -> row srow (within 8-row chunk), swizzled col-block
  const int srow = lane >> 3;
  const int scol = ((lane & 7) ^ srow) << 3;    // elems
  // frag-read swizzle: row m -> m&7 == l16&7
  const int rs   = l16 & 7;
  const int cb0  = (quad ^ rs) << 3;            // k/d block 0..31
  const int cb1  = ((quad + 4) ^ rs) << 3;      // k/d block 32..63

  f32x4 zero4 = {0.f, 0.f, 0.f, 0.f};
  const int b = bh >> 4, h = bh & 15;

  auto stage = [&](int kt, int bsel) {
    const bf16* ks = khead + (size_t)kt * 4096;   // (s,d) rows
    const bf16* vs = vhead + kt * 64;             // (d,s) cols
#pragma unroll
    for (int c = 0; c < 2; ++c) {
      const int chunk = (w << 1) + c;             // 0..7, 8 rows each
      const int row = (chunk << 3) + srow;
      gload_lds16(ks + row * 64 + scol,          &sK[bsel][chunk * 512]);
      gload_lds16(vs + (size_t)row * 2048 + scol, &sV[bsel][chunk * 512]);
    }
  };

  for (int pass = 0; pass < 2; ++pass) {
    const int qt = pass ? (31 - p) : p;
    const int nk = qt + 1;

    // Q frags straight from global (once per pass)
    const bf16* qsrc = Qb + head + (size_t)qt * 4096;
    bf16x8 aq0 = *(const bf16x8*)&qsrc[(w * 16 + l16) * 64 + quad * 8];
    bf16x8 aq1 = *(const bf16x8*)&qsrc[(w * 16 + l16) * 64 + 32 + quad * 8];

    f32x4 o[4] = {zero4, zero4, zero4, zero4};
    float mi[4] = {-3.0e38f, -3.0e38f, -3.0e38f, -3.0e38f};
    float li[4] = {0.f, 0.f, 0.f, 0.f};
    const int qrow = qt * 64 + w * 16 + quad * 4;

    __syncthreads();            // prev pass's readers done before restaging
    stage(0, 0);

    for (int kt = 0; kt < nk; ++kt) {
      __syncthreads();          // drains DMA for buf[kt&1]; flips buffers
      if (kt + 1 < nk) stage(kt + 1, (kt + 1) & 1);   // overlaps compute below

      const bf16* bK = sK[kt & 1];
      const bf16* bV = sV[kt & 1];

      // S = Q K^T (base-2 domain, Q pre-scaled)
      f32x4 sv[4];
#pragma unroll
      for (int i = 0; i < 4; ++i) {
        const int m = i * 16 + l16;
        bf16x8 k0 = *(const bf16x8*)&bK[m * 64 + cb0];
        bf16x8 k1 = *(const bf16x8*)&bK[m * 64 + cb1];
        f32x4 cacc = zero4;
        cacc = __builtin_amdgcn_mfma_f32_16x16x32_bf16(aq0, k0, cacc, 0, 0, 0);
        cacc = __builtin_amdgcn_mfma_f32_16x16x32_bf16(aq1, k1, cacc, 0, 0, 0);
        sv[i] = cacc;
      }

      if (kt == qt) {           // diagonal tile: causal mask
#pragma unroll
        for (int i = 0; i < 4; ++i) {
          int kcol = kt * 64 + i * 16 + l16;
#pragma unroll
          for (int r = 0; r < 4; ++r)
            sv[i][r] = (kcol > qrow + r) ? -3.0e38f : sv[i][r];
        }
      }

      // online softmax; row r owned by the 16 lanes of this quad
      float pv[4][4];
#pragma unroll
      for (int r = 0; r < 4; ++r) {
        float vr = fmaxf(fmaxf(sv[0][r], sv[1][r]), fmaxf(sv[2][r], sv[3][r]));
#pragma unroll
        for (int off = 1; off < 16; off <<= 1) vr = fmaxf(vr, __shfl_xor(vr, off));
        float mn = fmaxf(mi[r], vr);
        float al = exp2f(mi[r] - mn);
        float rsum = 0.f;
#pragma unroll
        for (int i = 0; i < 4; ++i) {
          float pe = exp2f(sv[i][r] - mn);
          pv[i][r] = pe;
          rsum += pe;
        }
#pragma unroll
        for (int off = 1; off < 16; off <<= 1) rsum += __shfl_xor(rsum, off);
        li[r] = li[r] * al + rsum;
        mi[r] = mn;
#pragma unroll
        for (int i = 0; i < 4; ++i) o[i][r] *= al;
      }

      // P: C-layout -> wave-private LDS strip -> A-layout (no barrier needed)
#pragma unroll
      for (int i = 0; i < 4; ++i)
#pragma unroll
        for (int r = 0; r < 4; ++r)
          sP[(w * 16 + quad * 4 + r) * 72 + i * 16 + l16] = (bf16)pv[i][r];

      bf16x8 ap0 = *(const bf16x8*)&sP[(w * 16 + l16) * 72 + quad * 8];
      bf16x8 ap1 = *(const bf16x8*)&sP[(w * 16 + l16) * 72 + 32 + quad * 8];
#pragma unroll
      for (int i = 0; i < 4; ++i) {   // O += P V using V^T rows
        const int m = i * 16 + l16;
        bf16x8 v0 = *(const bf16x8*)&bV[m * 64 + cb0];
        bf16x8 v1 = *(const bf16x8*)&bV[m * 64 + cb1];
        o[i] = __builtin_amdgcn_mfma_f32_16x16x32_bf16(ap0, v0, o[i], 0, 0, 0);
        o[i] = __builtin_amdgcn_mfma_f32_16x16x32_bf16(ap1, v1, o[i], 0, 0, 0);
      }
    }

    // epilogue for this pass
#pragma unroll
    for (int r = 0; r < 4; ++r) {
      float inv = 1.0f / li[r];
      int s = qt * 64 + w * 16 + quad * 4 + r;
      size_t base = ((size_t)(b * 2048 + s)) * 1024 + h * 64;
#pragma unroll
      for (int i = 0; i < 4; ++i)
        Yb[base + i * 16 + l16] = (bf16)(o[i][r] * inv);
    }
  }
}

// ---------------------------------------------------------------------------
extern "C" void kernel_launch(void* const* d_in, const int* in_sizes, int n_in,
                              void* d_out, int out_size, void* d_ws, size_t ws_size,
                              hipStream_t stream) {
  (void)in_sizes; (void)n_in; (void)out_size; (void)ws_size;
  const float* x    = (const float*)d_in[0];
  const float* wqkv = (const float*)d_in[1];
  const float* wo   = (const float*)d_in[2];
  float* out = (float*)d_out;
  char* ws = (char*)d_ws;

  bf16* Xb    = (bf16*)(ws + XB_OFF);
  bf16* Wqkvb = (bf16*)(ws + WQKV_OFF);
  bf16* Wob   = (bf16*)(ws + WO_OFF);
  bf16* Qb    = (bf16*)(ws + QB_OFF);
  bf16* Kb    = (bf16*)(ws + KB_OFF);
  bf16* Vtb   = (bf16*)(ws + VT_OFF);
  bf16* Yb    = (bf16*)(ws + YB_OFF);
  float* cosT = (float*)(ws + COS_OFF);
  float* sinT = (float*)(ws + SIN_OFF);

  rope_table<<<(2048 * 32) / 256, 256, 0, stream>>>(cosT, sinT);
  cvt_f32_bf16<<<4096, 256, 0, stream>>>(x,    Xb,    (4096 * 1024) / 4);
  cvt_f32_bf16<<<3072, 256, 0, stream>>>(wqkv, Wqkvb, (3072 * 1024) / 4);
  cvt_f32_bf16<<<1024, 256, 0, stream>>>(wo,   Wob,   (1024 * 1024) / 4);

  gemm_nt<0><<<dim3(24, 32), 256, 0, stream>>>(Xb, Wqkvb, nullptr, Qb, Kb, Vtb,
                                               cosT, sinT, 4096, 3072, 1024);
  attn_fwd<<<dim3(16, 32), 256, 0, stream>>>(Qb, Kb, Vtb, Yb);
  gemm_nt<1><<<dim3(8, 32), 256, 0, stream>>>(Yb, Wob, out, nullptr, nullptr, nullptr,
                                              nullptr, nullptr, 4096, 1024, 1024);
}